// Round 17
// baseline (81.157 us; speedup 1.0000x reference)
//
#include <hip/hip_runtime.h>

#define NEWL 150
#define EMBD 64
#define NCOL 256
#define CIMU 48
#define CEMG 16

#define KIMU (NEWL * CIMU)  // 7200
#define KEMG (NEWL * CEMG)  // 2400
#define KSTI 225            // total k-steps (32-wide) imu
#define KSTE 75             // total k-steps emg
#define NCI 5               // imu s-chunks (15 groups each)
#define NCE 3               // emg s-chunks (9/8/8 groups)

typedef __bf16 bf16x8_t __attribute__((ext_vector_type(8)));
typedef __bf16 bf16x4_t __attribute__((ext_vector_type(4)));
typedef float f32x4_t __attribute__((ext_vector_type(4)));

__device__ __forceinline__ f32x4_t mfma16(bf16x8_t a, bf16x8_t b, f32x4_t c) {
  return __builtin_amdgcn_mfma_f32_16x16x32_bf16(a, b, c, 0, 0, 0);
}

// ---------- K0: combined weights packed in MFMA B-fragment order + bias partials.
// W_pack[cb][ks][lane=h*16+(col&15)][u]  where k = ks*32 + h*8 + u
template <int C, int KST>
__device__ void wcomb_body(const float* __restrict__ wemb,
                           const float* __restrict__ wreg_src,
                           __bf16* __restrict__ wpk, int s, int j) {
  float wreg[EMBD];
#pragma unroll
  for (int e = 0; e < EMBD; ++e) wreg[e] = wreg_src[(size_t)e * NCOL];
  const int cb = j >> 4, lr = j & 15;
#pragma unroll
  for (int q = 0; q < C / 8; ++q) {
    const int kq = (s * C) / 8 + q;
    const int ks = kq >> 2, h = kq & 3;
    bf16x8_t tv;
#pragma unroll
    for (int u = 0; u < 8; ++u) {
      const float* we = wemb + (q * 8 + u) * EMBD;
      float acc = 0.f;
#pragma unroll
      for (int e = 0; e < EMBD; ++e) acc = fmaf(we[e], wreg[e], acc);
      tv[u] = (__bf16)acc;
    }
    *(bf16x8_t*)(wpk + (((size_t)cb * KST + ks) * 64 + h * 16 + lr) * 8) = tv;
  }
}

__global__ __launch_bounds__(256) void wcomb_kernel(
    const float* __restrict__ w_emb_imu, const float* __restrict__ w_emb_emg,
    const float* __restrict__ b_emb_imu, const float* __restrict__ b_emb_emg,
    const float* __restrict__ w_proj,
    __bf16* __restrict__ wpk_imu, __bf16* __restrict__ wpk_emg,
    float* __restrict__ bpart) {
  const int s = blockIdx.x;   // 0..149
  const int m = blockIdx.y;   // 0 = imu, 1 = emg
  const int j = threadIdx.x;  // output column 0..255
  const float* wp_base = w_proj + (size_t)s * EMBD * NCOL + j;
  const float* be = (m == 0) ? b_emb_imu : b_emb_emg;
  float bacc = 0.f;
#pragma unroll
  for (int e = 0; e < EMBD; ++e) bacc = fmaf(be[e], wp_base[(size_t)e * NCOL], bacc);
  bpart[((size_t)m * NEWL + s) * NCOL + j] = bacc;
  if (m == 0)
    wcomb_body<CIMU, KSTI>(w_emb_imu, wp_base, wpk_imu, s, j);
  else
    wcomb_body<CEMG, KSTE>(w_emb_emg, wp_base, wpk_emg, s, j);
}

// ---------- K1: fused ragged-interp + MFMA GEMM, 512-thread blocks.
// One block = (32-row m-tile, FULL 256 cols, s-chunk); 8 waves = 8 col-planes.
// (5+3) chunks x 64 m-tiles = 512 blocks = EXACTLY 2 blocks/CU, balanced.
// Distance-1 pipeline, static slots, VGPR<=128 via launch_bounds(512,2).
__global__ __launch_bounds__(512, 2) void fused_kernel(
    const float* __restrict__ x_imu, const float* __restrict__ x_emg,
    const int* __restrict__ lens,
    const __bf16* __restrict__ wpk_imu, const __bf16* __restrict__ wpk_emg,
    const float* __restrict__ b_proj, const float* __restrict__ bpart,
    float* __restrict__ p_imu, float* __restrict__ p_emg,
    float* __restrict__ bias, int B, int T) {
  const int bid = blockIdx.x;
  const int span = B >> 5;               // 64 m-tiles per chunk
  const int nblk = (NCE + NCI) * span;   // 512 compute blocks
  if (bid == nblk) {  // bias tail block
    const int j = threadIdx.x;
    if (j < NCOL) {
#pragma unroll
      for (int m = 0; m < 2; ++m) {
        float acc = b_proj[j];
        for (int s = 0; s < NEWL; ++s)
          acc += bpart[((size_t)m * NEWL + s) * NCOL + j];
        bias[m * NCOL + j] = acc;
      }
    }
    return;
  }

  __shared__ __bf16 lds[2][2][3][512];  // [buf][row-plane][ks][lane*8]

  const int tid = threadIdx.x;
  const int wv = tid >> 6, l = tid & 63;

  const int cs = bid / span;
  const int mt = bid - cs * span;
  const bool is_imu = cs >= NCE;
  const int c = is_imu ? cs - NCE : cs;

  // chunk geometry (group = 3 ksteps; imu: 2 s/group, emg: 6 s/group)
  int g0, NG;
  if (is_imu) { g0 = 15 * c; NG = 15; }                     // 5 x 15 = 75 groups
  else        { g0 = (c == 0) ? 0 : (9 + 8 * (c - 1)); NG = c ? 8 : 9; }  // 9/8/8
  const int ks0 = 3 * g0;
  const int sb = is_imu ? 2 * g0 : 6 * g0;

  const __bf16* Wp = is_imu ? wpk_imu : wpk_emg;
  const int KST = is_imu ? KSTI : KSTE;
  float* P = is_imu ? (p_imu + (size_t)c * B * NCOL) : (p_emg + (size_t)c * B * NCOL);

  const size_t PS = (size_t)KST * 512;  // B fragment-plane stride (bf16)
  // wave wv owns col-planes wv*2, wv*2+1 (16 cols each -> 32 cols/wave)
  const __bf16* bg = Wp + ((size_t)(wv * 2) * KST + ks0) * 512 + l * 8;

  // gather thread mappings
  // imu: 8 thr/(b,s): pid=tid>>3 (b4=pid&31, sl=pid>>5), row=(tid>>2)&1, q=tid&3
  const int q = tid & 3, rowb = (tid >> 2) & 1;
  const int pid = tid >> 3, b4 = pid & 31, sl = pid >> 5;
  // emg: 2 thr/(b,s): pid_e=tid>>1 (ble=pid_e/6, se=pid_e%6), row=tid&1; tid<384
  const int pid_e = tid >> 1;
  const int ble = pid_e / 6, se = pid_e - ble * 6, rowe = tid & 1;
  const bool act = is_imu || (tid < 384);
  const int b_g = mt * 32 + (is_imu ? b4 : (act ? ble : 0));
  int lenv = 1;
  float scale = 0.f;
  if (act) { lenv = lens[b_g]; scale = (float)lenv * (1.0f / 150.0f); }

  float gr[16];     // imu uses 12 (one row quarter x3), emg 16 (one row)
  float wS;         // lerp weight
  bf16x8_t bB[6];   // single B slot (2 planes x 3 ksteps)
  f32x4_t acc00 = {0.f, 0.f, 0.f, 0.f}, acc01 = acc00, acc10 = acc00, acc11 = acc00;

// imu gather: thread reads ONE row (i0 or i1 by rowb), quarter q: 3x float4.
#define ISSUE_GI(g2) do {                                                       \
    const int s_ = sb + (g2) * 2 + sl;                                          \
    float src_ = fmaxf(((float)s_ + 0.5f) * scale - 0.5f, 0.0f);                \
    int i0_ = min((int)src_, lenv - 1);                                         \
    int i1_ = min(i0_ + 1, lenv - 1);                                           \
    wS = src_ - (float)i0_;                                                     \
    const float* r_ =                                                           \
        x_imu + ((size_t)b_g * T + (rowb ? i1_ : i0_)) * CIMU + q * 4;          \
    _Pragma("unroll")                                                           \
    for (int t = 0; t < 3; ++t) {                                               \
      float4 v_ = *(const float4*)(r_ + t * 16);                                \
      gr[t * 4 + 0] = v_.x; gr[t * 4 + 1] = v_.y;                               \
      gr[t * 4 + 2] = v_.z; gr[t * 4 + 3] = v_.w;                               \
    }                                                                           \
  } while (0)

// lerp: partner (other row) is lane^4; row0 threads compute+write LDS.
#define LERP_WI(BUF) do {                                                       \
    const float wg_ = wS, om_ = 1.0f - wg_;                                     \
    _Pragma("unroll")                                                           \
    for (int t = 0; t < 3; ++t) {                                               \
      float p0_ = __shfl_xor(gr[t * 4 + 0], 4);                                 \
      float p1_ = __shfl_xor(gr[t * 4 + 1], 4);                                 \
      float p2_ = __shfl_xor(gr[t * 4 + 2], 4);                                 \
      float p3_ = __shfl_xor(gr[t * 4 + 3], 4);                                 \
      if (rowb == 0) {                                                          \
        bf16x4_t o_;                                                            \
        o_[0] = (__bf16)(gr[t * 4 + 0] * om_ + p0_ * wg_);                      \
        o_[1] = (__bf16)(gr[t * 4 + 1] * om_ + p1_ * wg_);                      \
        o_[2] = (__bf16)(gr[t * 4 + 2] * om_ + p2_ * wg_);                      \
        o_[3] = (__bf16)(gr[t * 4 + 3] * om_ + p3_ * wg_);                      \
        const int kq_ = sl * 6 + t * 2 + (q >> 1);                              \
        *(bf16x4_t*)(&lds[BUF][b4 >> 4][kq_ >> 2]                               \
                         [((kq_ & 3) * 16 + (b4 & 15)) * 8 + (q & 1) * 4]) = o_;\
      }                                                                         \
    }                                                                           \
  } while (0)

// emg gather: thread reads ONE row (i0 or i1 by rowe): 4x float4.
#define ISSUE_GE(g2) do { if (act) {                                            \
    const int s_ = sb + (g2) * 6 + se;                                          \
    float src_ = fmaxf(((float)s_ + 0.5f) * scale - 0.5f, 0.0f);                \
    int i0_ = min((int)src_, lenv - 1);                                         \
    int i1_ = min(i0_ + 1, lenv - 1);                                           \
    wS = src_ - (float)i0_;                                                     \
    const float* r_ = x_emg + ((size_t)b_g * T + (rowe ? i1_ : i0_)) * CEMG;    \
    _Pragma("unroll")                                                           \
    for (int t = 0; t < 4; ++t) {                                               \
      float4 v_ = *(const float4*)(r_ + t * 4);                                 \
      gr[t * 4 + 0] = v_.x; gr[t * 4 + 1] = v_.y;                               \
      gr[t * 4 + 2] = v_.z; gr[t * 4 + 3] = v_.w;                               \
    }                                                                           \
  } } while (0)

// emg lerp: partner lane^1; row0 thread writes 2 bf16x8.
#define LERP_WE(BUF) do { if (act) {                                            \
    const float wg_ = wS, om_ = 1.0f - wg_;                                     \
    _Pragma("unroll")                                                           \
    for (int t2 = 0; t2 < 2; ++t2) {                                            \
      float pv_[8];                                                             \
      _Pragma("unroll")                                                         \
      for (int u = 0; u < 8; ++u) pv_[u] = __shfl_xor(gr[t2 * 8 + u], 1);       \
      if (rowe == 0) {                                                          \
        bf16x8_t o_;                                                            \
        _Pragma("unroll")                                                       \
        for (int u = 0; u < 8; ++u)                                             \
          o_[u] = (__bf16)(gr[t2 * 8 + u] * om_ + pv_[u] * wg_);                \
        const int kq_ = se * 2 + t2;                                            \
        *(bf16x8_t*)(&lds[BUF][ble >> 4][kq_ >> 2]                              \
                         [((kq_ & 3) * 16 + (ble & 15)) * 8]) = o_;             \
      }                                                                         \
    }                                                                           \
  } } while (0)

#define ISSUE_B(g1) do {                                                        \
    const __bf16* pb_ = bg + (size_t)((g1) * 3) * 512;                          \
    _Pragma("unroll")                                                           \
    for (int ks = 0; ks < 3; ++ks) {                                            \
      bB[ks * 2 + 0] = *(const bf16x8_t*)(pb_ + (size_t)ks * 512);              \
      bB[ks * 2 + 1] = *(const bf16x8_t*)(pb_ + PS + (size_t)ks * 512);         \
    }                                                                           \
  } while (0)

#define COMPUTE(Pp) do {                                                        \
    _Pragma("unroll")                                                           \
    for (int ks = 0; ks < 3; ++ks) {                                            \
      bf16x8_t a0_ = *(const bf16x8_t*)(&lds[Pp][0][ks][l * 8]);                \
      bf16x8_t a1_ = *(const bf16x8_t*)(&lds[Pp][1][ks][l * 8]);                \
      acc00 = mfma16(a0_, bB[ks * 2 + 0], acc00);                               \
      acc01 = mfma16(a0_, bB[ks * 2 + 1], acc01);                               \
      acc10 = mfma16(a1_, bB[ks * 2 + 0], acc10);                               \
      acc11 = mfma16(a1_, bB[ks * 2 + 1], acc11);                               \
    }                                                                           \
  } while (0)

  // prologue: stage group 0, load B0
  if (is_imu) { ISSUE_GI(0); LERP_WI(0); }
  else        { ISSUE_GE(0); LERP_WE(0); }
  ISSUE_B(0);
  __syncthreads();

  for (int p = 0; p < NG; ++p) {
    const int more = (p + 1 < NG);
    if (more) { if (is_imu) ISSUE_GI(p + 1); else ISSUE_GE(p + 1); }
    COMPUTE(p & 1);
    if (more) ISSUE_B(p + 1);
    if (more) { if (is_imu) LERP_WI((p + 1) & 1); else LERP_WE((p + 1) & 1); }
    __syncthreads();
  }

  // epilogue: C/D col = lane&15, row = (lane>>4)*4 + reg
  const int lh = l >> 4, lr = l & 15;
  float* Pb = P + (size_t)(mt * 32 + lh * 4) * NCOL + wv * 32 + lr;
#pragma unroll
  for (int jj = 0; jj < 4; ++jj) {
    Pb[(size_t)jj * NCOL] = acc00[jj];
    Pb[(size_t)jj * NCOL + 16] = acc01[jj];
    Pb[(size_t)(16 + jj) * NCOL] = acc10[jj];
    Pb[(size_t)(16 + jj) * NCOL + 16] = acc11[jj];
  }
#undef ISSUE_GI
#undef LERP_WI
#undef ISSUE_GE
#undef LERP_WE
#undef ISSUE_B
#undef COMPUTE
}

// ---------- K2: sum split-K partials + bias -> d_out
__global__ __launch_bounds__(256) void combine_kernel(
    const float* __restrict__ bias, const float* __restrict__ p_imu,
    const float* __restrict__ p_emg, float* __restrict__ out, int B) {
  const int b = blockIdx.x, m = blockIdx.y, j = threadIdx.x;
  const size_t n = (size_t)B * NCOL;
  const size_t o = (size_t)b * NCOL + j;
  if (m == 0) {
    float v = bias[j];
#pragma unroll
    for (int c = 0; c < NCI; ++c) v += p_imu[c * n + o];
    out[o] = v;
  } else {
    float v = bias[NCOL + j];
#pragma unroll
    for (int c = 0; c < NCE; ++c) v += p_emg[c * n + o];
    out[n + o] = v;
  }
}

extern "C" void kernel_launch(void* const* d_in, const int* in_sizes, int n_in,
                              void* d_out, int out_size, void* d_ws, size_t ws_size,
                              hipStream_t stream) {
  const float* x_imu     = (const float*)d_in[0];
  const float* x_emg     = (const float*)d_in[1];
  const int*   lens      = (const int*)d_in[2];
  const float* w_emb_imu = (const float*)d_in[3];
  const float* b_emb_imu = (const float*)d_in[4];
  const float* w_emb_emg = (const float*)d_in[5];
  const float* b_emb_emg = (const float*)d_in[6];
  const float* w_proj    = (const float*)d_in[7];
  const float* b_proj    = (const float*)d_in[8];
  float* out = (float*)d_out;

  const int B = in_sizes[2];
  const int T = in_sizes[0] / (B * CIMU);

  char* ws = (char*)d_ws;
  __bf16* wpk_imu = (__bf16*)ws;  ws += (size_t)NCOL * KIMU * 2;
  __bf16* wpk_emg = (__bf16*)ws;  ws += (size_t)NCOL * KEMG * 2;
  float*  bias    = (float*)ws;   ws += 2 * NCOL * 4;
  float*  bpart   = (float*)ws;   ws += (size_t)2 * NEWL * NCOL * 4;
  float*  p_imu   = (float*)ws;   ws += (size_t)NCI * B * NCOL * 4;
  float*  p_emg   = (float*)ws;   ws += (size_t)NCE * B * NCOL * 4;

  wcomb_kernel<<<dim3(NEWL, 2), 256, 0, stream>>>(
      w_emb_imu, w_emb_emg, b_emb_imu, b_emb_emg, w_proj, wpk_imu, wpk_emg, bpart);
  const int span = B >> 5;                        // 64
  const int nblk = (NCE + NCI) * span + 1;        // 513
  fused_kernel<<<nblk, 512, 0, stream>>>(x_imu, x_emg, lens, wpk_imu, wpk_emg,
                                         b_proj, bpart, p_imu, p_emg, bias, B, T);
  combine_kernel<<<dim3(B, 2), 256, 0, stream>>>(bias, p_imu, p_emg, out, B);
}